// Round 11
// baseline (77.093 us; speedup 1.0000x reference)
//
#include <hip/hip_runtime.h>

#define NPTS 8192
#define NQ   2048
#define NBATCH 8
#define KNN  32
#define R2   0.04f   // fp32 cast of python 0.2**2
#define NQTOT (NBATCH * NQ)
#define PACK_F4 (NBATCH * NPTS)

// Pack pos (AoS, 12B stride) into float4(x,y,z,|p|^2). Norm with explicit
// round-to-nearest ops, no FMA contraction, reference order: (x*x+y*y)+z*z.
__global__ __launch_bounds__(256)
void gg_prep(const float* __restrict__ pos, float4* __restrict__ pack, int total) {
    int i = blockIdx.x * blockDim.x + threadIdx.x;
    if (i >= total) return;
    float x = pos[i * 3 + 0];
    float y = pos[i * 3 + 1];
    float z = pos[i * 3 + 2];
    float n = __fadd_rn(__fadd_rn(__fmul_rn(x, x), __fmul_rn(y, y)), __fmul_rn(z, z));
    pack[i] = make_float4(x, y, z, n);
}

// Branch-free test of 128 points [SUBI,SUBI+128) for one query: lane tests
// SUBI+lane (PA) and SUBI+64+lane (PB). The two op-trees are interleaved as
// identical adjacent scalar ops so the SLP vectorizer can emit packed
// v_pk_mul_f32/v_pk_add_f32 (per-element rounding identical to scalar).
// Distance matches reference op order exactly:
//   s = (cn + pn) - 2*((cx*px + cy*py) + cz*pz)
// Hits compact into an LDS slot row via ONE unconditional ds_write each with
// a clamped address (non-keep/overflow lanes hit a per-lane dump slot).
// No first-hit tracking: pad value = slot 0, read back in the epilogue
// (centroid's own distance is exactly 0 in this op order, so col >= 1).
#define TEST2(C, COL, SQ, PA, PB, SUBI)                                            \
    {                                                                              \
        float mxA = __fmul_rn((C).x, (PA).x), mxB = __fmul_rn((C).x, (PB).x);      \
        float myA = __fmul_rn((C).y, (PA).y), myB = __fmul_rn((C).y, (PB).y);      \
        float axA = __fadd_rn(mxA, myA),      axB = __fadd_rn(mxB, myB);           \
        float mzA = __fmul_rn((C).z, (PA).z), mzB = __fmul_rn((C).z, (PB).z);      \
        float dA  = __fadd_rn(axA, mzA),      dB  = __fadd_rn(axB, mzB);           \
        float nA  = __fadd_rn((C).w, (PA).w), nB  = __fadd_rn((C).w, (PB).w);      \
        float tA  = __fmul_rn(2.0f, dA),      tB  = __fmul_rn(2.0f, dB);           \
        float sA  = __fsub_rn(nA, tA),        sB  = __fsub_rn(nB, tB);             \
        bool kA = !(sA > R2), kB = !(sB > R2);                                     \
        unsigned long long mA = __ballot(kA), mB = __ballot(kB);                   \
        int pcA = (int)__popcll(mA);                                               \
        int pfA = (int)__builtin_amdgcn_mbcnt_hi((unsigned)(mA >> 32),             \
                      __builtin_amdgcn_mbcnt_lo((unsigned)mA, 0u));                \
        int pfB = (int)__builtin_amdgcn_mbcnt_hi((unsigned)(mB >> 32),             \
                      __builtin_amdgcn_mbcnt_lo((unsigned)mB, 0u));                \
        int slA = (COL) + pfA;                                                     \
        int slB = (COL) + pcA + pfB;                                               \
        int aA  = (kA && slA < KNN) ? slA : (KNN + 2 + lane);                      \
        int aB  = (kB && slB < KNN) ? slB : (KNN + 2 + lane);                      \
        (SQ)[aA] = (SUBI) + lane;                                                  \
        (SQ)[aB] = (SUBI) + 64 + lane;                                             \
        (COL) += pcA + (int)__popcll(mB);                                          \
    }

// One wave per TWO adjacent queries (same batch). 256 pts/iteration, loads
// issued one iteration ahead (R4/R10-proven skeleton); per-query wave-uniform
// guard once per 256 pts; early exit when both queries have 32 hits.
// 4 waves/block, 2048 blocks = 8192 waves (8/SIMD). No atomics.
__global__ __launch_bounds__(256)
void gg_ballquery(const float4* __restrict__ pack,
                  const int* __restrict__ centroids,
                  int* __restrict__ out) {
    const int wid  = threadIdx.x >> 6;
    const int lane = threadIdx.x & 63;
    const int w    = blockIdx.x * 4 + wid;          // wave id: 0 .. 8191
    const int q0   = w * 2;                         // two consecutive queries
    const int b    = q0 >> 11;                      // batch

    // Per-wave, per-query slot rows: [0,32) results, [34,98) per-lane dump.
    __shared__ int slds[4][2][128];
    int* __restrict__ sqA = &slds[wid][0][0];
    int* __restrict__ sqB = &slds[wid][1][0];

    const float4* __restrict__ pp = pack + b * NPTS;

    const float4 cA = pp[centroids[q0]];
    const float4 cB = pp[centroids[q0 + 1]];

    int* __restrict__ oA = out + q0 * KNN;
    int* __restrict__ oB = oA + KNN;

    int colA = 0, colB = 0;

    // Prefetch iteration 0 (points [0, 256))
    float4 r0 = pp[lane];
    float4 r1 = pp[lane + 64];
    float4 r2 = pp[lane + 128];
    float4 r3 = pp[lane + 192];

    #pragma unroll 1
    for (int base = 0; base < NPTS; base += 256) {
        float4 p0 = r0, p1 = r1, p2 = r2, p3 = r3;
        if (base + 256 < NPTS) {                    // prefetch next 256 points
            r0 = pp[base + 256 + lane];
            r1 = pp[base + 320 + lane];
            r2 = pp[base + 384 + lane];
            r3 = pp[base + 448 + lane];
        }

        if (colA < KNN) {
            TEST2(cA, colA, sqA, p0, p1, base);
            TEST2(cA, colA, sqA, p2, p3, base + 128);
        }
        if (colB < KNN) {
            TEST2(cB, colB, sqB, p0, p1, base);
            TEST2(cB, colB, sqB, p2, p3, base + 128);
        }
        if (colA >= KNN && colB >= KNN) break;      // wave-uniform early exit
    }

    // Epilogue: slots [col,32) pad with slot 0 (the first in-radius index).
    // Same wave wrote the LDS — lockstep, no barrier needed.
    if (lane < KNN) {
        oA[lane] = sqA[(lane < colA) ? lane : 0];
        oB[lane] = sqB[(lane < colB) ? lane : 0];
    }
}

extern "C" void kernel_launch(void* const* d_in, const int* in_sizes, int n_in,
                              void* d_out, int out_size, void* d_ws, size_t ws_size,
                              hipStream_t stream) {
    const float* pos       = (const float*)d_in[0];   // (8, 8192, 3) f32
    const int*   centroids = (const int*)d_in[1];     // (8, 2048) int32
    int*         out       = (int*)d_out;             // (8, 2048, 32) int32

    float4* pack = (float4*)d_ws;                     // 1 MiB scratch

    gg_prep<<<dim3((PACK_F4 + 255) / 256), dim3(256), 0, stream>>>(pos, pack, PACK_F4);

    const int nw = NQTOT / 2;                         // 8192 waves, 4 per block
    gg_ballquery<<<dim3(nw / 4), dim3(256), 0, stream>>>(pack, centroids, out);
}